// Round 2
// baseline (258.082 us; speedup 1.0000x reference)
//
#include <hip/hip_runtime.h>
#include <math.h>

// spe_self_atten: out[b] = softmax( (Xb Xb^T) / max(n_i n_j, eps) ) Xb + Xb
// B=256, C=200, L=1024. f32 in/out, bf16 MFMA internally. Residual via P += I.
// Round 2: 2 blocks per batch (grid 512) -> 2 blocks/CU (80KB LDS each) to fix
// the 21% occupancy / barrier-latency bound seen in round 1.

typedef unsigned int uint32;
typedef __attribute__((ext_vector_type(8))) short bf16x8;   // 8 bf16 (4 VGPRs)
typedef __attribute__((ext_vector_type(4))) float f32x4;    // MFMA accum

#define CC 200
#define LL 1024
#define EPSV 1e-8f
#define PLSTR 116   // P row stride (dw): 232 bf16 cols, !=0 mod 32, ==0 mod 4
#define XASTR 36    // phase-1 slab row stride (dw): 72 bf16
#define XBSTR 116   // phase-2 B col stride (dw): 116 kpair-dwords

__device__ __forceinline__ uint32 bfb(float f) {
  // f32 -> bf16 bits, round-to-nearest-even
  uint32 u = __float_as_uint(f);
  u += 0x7fffu + ((u >> 16) & 1u);
  return u >> 16;
}

__global__ __launch_bounds__(512, 4)
void spe_attn_kernel(const float* __restrict__ x, float* __restrict__ out) {
  const int tid  = threadIdx.x;
  const int lane = tid & 63;
  const int w    = tid >> 6;       // wave 0..7
  const int lm   = lane & 15;
  const int lg   = lane >> 4;
  const int bidx = blockIdx.x;
  const int batch = bidx >> 1;
  const int half  = bidx & 1;
  const float* xb = x + (size_t)batch * (CC * LL);
  float* ob       = out + (size_t)batch * (CC * LL);

  const int hb     = half ? 7 : 0;   // first owned global row-tile
  const int ntiles = half ? 6 : 7;   // row tiles owned by this block
  const int dbase  = half ? 0 : 7;   // diag tiles computed for the other half
  const int ndiag  = 13 - ntiles;

  // LDS (dwords), 20480 dw = 81920 B -> exactly 2 blocks/CU:
  //  pl   [0,12992)      : P bf16, 112 rows x 232 cols (116 dw stride).
  //                        dw 112/113 of each row hold packed norms[0..207].
  //  xa   [12992,20480)  : phase-1 slab, 208 rows x 72 bf16 (36 dw)
  //  xbuf [12992,20416)  : phase-2 chunk, col-major 64 cols x 116 dw (aliases xa)
  __shared__ uint32 LDS[20480];
  uint32* pl   = LDS;
  uint32* xa   = LDS + 12992;
  uint32* xbuf = LDS + 12992;
  #define NRM(g) (*(float*)&pl[((g) >> 1) * PLSTR + 112 + ((g) & 1)])

  // ---------------- Phase 1: Gram rows for this half -------------------------
  const f32x4 fz = {0.f, 0.f, 0.f, 0.f};
  f32x4 acc[13];
  #pragma unroll
  for (int j = 0; j < 13; ++j) acc[j] = fz;

  // zero slab pad rows 200..207 (stay zero; staging writes rows < 200)
  if (tid < 288) xa[7200 + tid] = 0u;

  float4 vst[7];
  #pragma unroll
  for (int i = 0; i < 7; ++i) {     // stage slab 0 (k=0..63)
    int idx = tid + i * 512;
    if (idx < 3200) {
      int row = idx >> 4, c4 = idx & 15;
      vst[i] = *(const float4*)(xb + row * LL + c4 * 4);
    }
  }
  #pragma unroll
  for (int i = 0; i < 7; ++i) {
    int idx = tid + i * 512;
    if (idx < 3200) {
      int row = idx >> 4, c4 = idx & 15;
      uint2 wv;
      wv.x = bfb(vst[i].x) | (bfb(vst[i].y) << 16);
      wv.y = bfb(vst[i].z) | (bfb(vst[i].w) << 16);
      *(uint2*)&xa[row * XASTR + c4 * 2] = wv;
    }
  }

  for (int s = 0; s < 16; ++s) {
    __syncthreads();                 // slab s visible
    if (s + 1 < 16) {                // reg-prefetch next slab (latency under MFMA)
      #pragma unroll
      for (int i = 0; i < 7; ++i) {
        int idx = tid + i * 512;
        if (idx < 3200) {
          int row = idx >> 4, c4 = idx & 15;
          vst[i] = *(const float4*)(xb + row * LL + (s + 1) * 64 + c4 * 4);
        }
      }
    }
    #pragma unroll
    for (int ks = 0; ks < 2; ++ks) {
      if (w < ntiles) {
        bf16x8 a = *(const bf16x8*)&xa[((hb + w) * 16 + lm) * XASTR + ks * 16 + lg * 4];
        #pragma unroll
        for (int ct = 0; ct < 13; ++ct) {
          bf16x8 b = *(const bf16x8*)&xa[(ct * 16 + lm) * XASTR + ks * 16 + lg * 4];
          acc[ct] = __builtin_amdgcn_mfma_f32_16x16x32_bf16(a, b, acc[ct], 0, 0, 0);
        }
      } else if (w == ntiles) {      // spare wave: other half's diagonal tiles
        #pragma unroll
        for (int d = 0; d < 7; ++d) {
          if (d < ndiag) {
            bf16x8 f = *(const bf16x8*)&xa[((dbase + d) * 16 + lm) * XASTR + ks * 16 + lg * 4];
            acc[d] = __builtin_amdgcn_mfma_f32_16x16x32_bf16(f, f, acc[d], 0, 0, 0);
          }
        }
      }
    }
    __syncthreads();                 // all reads of slab s done
    if (s + 1 < 16) {                // write staged regs (single buffer)
      #pragma unroll
      for (int i = 0; i < 7; ++i) {
        int idx = tid + i * 512;
        if (idx < 3200) {
          int row = idx >> 4, c4 = idx & 15;
          uint2 wv;
          wv.x = bfb(vst[i].x) | (bfb(vst[i].y) << 16);
          wv.y = bfb(vst[i].z) | (bfb(vst[i].w) << 16);
          *(uint2*)&xa[row * XASTR + c4 * 2] = wv;
        }
      }
    }
  }

  // ---------------- norms (all 208) from Gram diagonals ----------------------
  if (w < ntiles) {
    const int t = hb + w;
    #pragma unroll
    for (int ct = 0; ct < 13; ++ct) {
      if (ct == t) {
        #pragma unroll
        for (int r = 0; r < 4; ++r) {
          int ri = lg * 4 + r;
          if (lm == ri) NRM(t * 16 + ri) = sqrtf(acc[ct][r]);
        }
      }
    }
  } else if (w == ntiles) {
    #pragma unroll
    for (int d = 0; d < 7; ++d) {
      if (d < ndiag) {
        int t = dbase + d;
        #pragma unroll
        for (int r = 0; r < 4; ++r) {
          int ri = lg * 4 + r;
          if (lm == ri) NRM(t * 16 + ri) = sqrtf(acc[d][r]);
        }
      }
    }
  }
  __syncthreads();

  // ---------------- softmax rows + (P+I) -> LDS bf16 (own rows only) ---------
  bf16x8 pa[7];                      // phase-2 A fragments, hoisted to regs
  if (w < ntiles) {
    float cn[13];
    #pragma unroll
    for (int ct = 0; ct < 13; ++ct) cn[ct] = NRM(ct * 16 + lm);

    #pragma unroll
    for (int r = 0; r < 4; ++r) {
      int grow = (hb + w) * 16 + lg * 4 + r;
      int lrow = w * 16 + lg * 4 + r;
      float rn = NRM(grow);
      float sv[13];
      float m = -INFINITY;
      #pragma unroll
      for (int ct = 0; ct < 13; ++ct) {
        int gc = ct * 16 + lm;
        float sval = acc[ct][r] / fmaxf(rn * cn[ct], EPSV);
        sval = (gc < CC) ? sval : -INFINITY;
        sv[ct] = sval;
        m = fmaxf(m, sval);
      }
      #pragma unroll
      for (int off = 1; off < 16; off <<= 1) m = fmaxf(m, __shfl_xor(m, off));
      float sum = 0.f;
      #pragma unroll
      for (int ct = 0; ct < 13; ++ct) {
        float e = __expf(sv[ct] - m);
        sv[ct] = e;
        sum += e;
      }
      #pragma unroll
      for (int off = 1; off < 16; off <<= 1) sum += __shfl_xor(sum, off);
      float inv = 1.0f / sum;
      #pragma unroll
      for (int ct = 0; ct < 13; ++ct) {
        int gc = ct * 16 + lm;
        float p = sv[ct] * inv + ((gc == grow) ? 1.0f : 0.0f);   // P += I
        uint32 pb = bfb(p);
        uint32 qb = (uint32)__shfl_xor((int)pb, 1);
        if (!(lane & 1)) pl[lrow * PLSTR + ct * 8 + (lm >> 1)] = pb | (qb << 16);
      }
    }
    // zero P cols 200..223 (dw 100..111) for this row-block
    #pragma unroll
    for (int i = 0; i < 4; ++i) {
      int idx = lane + i * 64;
      int rr = idx >> 4, c = idx & 15;
      if (c < 12) pl[(w * 16 + rr) * PLSTR + 100 + c] = 0u;
    }
    // A-fragments: wave reads only rows it just wrote (intra-wave, no barrier)
    #pragma unroll
    for (int ks = 0; ks < 7; ++ks)
      pa[ks] = *(const bf16x8*)&pl[(w * 16 + lm) * PLSTR + ks * 16 + lg * 4];
  }

  // ---------------- Phase 2: out rows = (P+I) @ Xb, 16 chunks of 64 cols -----
  for (int nc = 0; nc < 16; ++nc) {
    const int n0 = nc * 64;
    __syncthreads();                 // prev chunk consumed (nc=0: phase-1 xa dead)
    // stage Xb[:, n0:n0+64] col-major kpair-packed:
    // xbuf[col*116 + kp^sw] = bf16(x[2kp][n0+col]) | bf16(x[2kp+1][n0+col])<<16
    #pragma unroll
    for (int pass = 0; pass < 14; ++pass) {
      int kp = pass * 8 + w;         // 0..111 (K padded to 224; rows>=200 -> 0)
      int r0 = kp * 2, r1 = r0 + 1;
      float va = (r0 < CC) ? xb[r0 * LL + n0 + lane] : 0.f;
      float vb = (r1 < CC) ? xb[r1 * LL + n0 + lane] : 0.f;
      int sw = ((lane >> 3) & 3) << 2;   // XOR swizzle, bits 2..3 only (range-safe)
      xbuf[lane * XBSTR + (kp ^ sw)] = bfb(va) | (bfb(vb) << 16);
    }
    __syncthreads();

    if (w < ntiles) {
      f32x4 acc2[4] = {fz, fz, fz, fz};
      #pragma unroll
      for (int ks = 0; ks < 7; ++ks) {
        #pragma unroll
        for (int ct = 0; ct < 4; ++ct) {
          int col = ct * 16 + lm;
          int kpb = ks * 16 + lg * 4;
          int sw = ((col >> 3) & 3) << 2;
          bf16x8 b = *(const bf16x8*)&xbuf[col * XBSTR + (kpb ^ sw)];
          acc2[ct] = __builtin_amdgcn_mfma_f32_16x16x32_bf16(pa[ks], b, acc2[ct], 0, 0, 0);
        }
      }
      #pragma unroll
      for (int ct = 0; ct < 4; ++ct) {
        #pragma unroll
        for (int r = 0; r < 4; ++r) {
          int grow = (hb + w) * 16 + lg * 4 + r;
          if (grow < CC) ob[grow * LL + n0 + ct * 16 + lm] = acc2[ct][r];
        }
      }
    }
  }
  #undef NRM
}

extern "C" void kernel_launch(void* const* d_in, const int* in_sizes, int n_in,
                              void* d_out, int out_size, void* d_ws, size_t ws_size,
                              hipStream_t stream) {
  const float* x = (const float*)d_in[0];
  float* out = (float*)d_out;
  const int B = in_sizes[0] / (CC * LL);   // 256
  spe_attn_kernel<<<dim3(2 * B), dim3(512), 0, stream>>>(x, out);
}

// Round 3
// 157.545 us; speedup vs baseline: 1.6382x; 1.6382x over previous
//
#include <hip/hip_runtime.h>
#include <math.h>

// spe_self_atten: out[b] = softmax( (Xb Xb^T) / max(n_i n_j, eps) ) Xb + Xb
// B=256, C=200, L=1024. f32 in/out, bf16 MFMA internally. Residual via P += I.
// Round 3: back to 1 block/batch (round-1 structure, which measured cleanest),
// phase-2 rebuilt: col-major kpair LDS (stride 132 == 4 mod 32, no XOR),
// ds_read_b128 B-fragments (half the LDS cycles of 4x b32), both A row-tiles
// hoisted (2 MFMA per B-read), T14 issue-early/write-late chunk staging.

typedef unsigned int uint32;
typedef __attribute__((ext_vector_type(8))) short bf16x8;   // 8 bf16 (4 VGPRs)
typedef __attribute__((ext_vector_type(4))) float f32x4;    // MFMA accum

#define CC 200
#define LL 1024
#define EPSV 1e-8f
#define PLSTR 116   // P row stride (dw)
#define XASTR 36    // phase-1 slab row stride (dw), == 4 mod 32
#define XBSTR 132   // phase-2 col stride (dw), == 4 mod 32, >= 112 kpairs

__device__ __forceinline__ uint32 bfb(float f) {
  // f32 -> bf16 bits, round-to-nearest-even
  uint32 u = __float_as_uint(f);
  u += 0x7fffu + ((u >> 16) & 1u);
  return u >> 16;
}

__global__ __launch_bounds__(512, 1)
void spe_attn_kernel(const float* __restrict__ x, float* __restrict__ out) {
  const int tid  = threadIdx.x;
  const int lane = tid & 63;
  const int w    = tid >> 6;       // wave 0..7
  const int lm   = lane & 15;
  const int lg   = lane >> 4;
  const int bidx = blockIdx.x;
  const float* xb = x + (size_t)bidx * (CC * LL);
  float* ob       = out + (size_t)bidx * (CC * LL);

  // LDS layout (dwords), total 39312 dw = 157,248 B:
  //  pl    [0,24128)      : P bf16, 208 rows x 232 cols (116 dw stride)
  //  xa0   [24128,31616)  : phase-1 slab buf A, 208 rows x 72 bf16 (36 dw)
  //  xa1   [31616,39104)  : phase-1 slab buf B
  //  xbuf  [24128,32576)  : phase-2 chunk, col-major 64 cols x 132 dw (aliases xa)
  //  norms [39104,39312)  : 208 floats
  __shared__ uint32 LDS[39312];
  uint32* pl    = LDS;
  uint32* xa0   = LDS + 24128;
  uint32* xa1   = LDS + 31616;
  uint32* xbuf  = LDS + 24128;
  float*  norms = (float*)(LDS + 39104);

  const bool two = (w < 5);            // waves 0..4 own row-tiles {w, w+8}
  const int rb0 = w;
  const int rb1 = two ? (w + 8) : w;

  // ---------------- Phase 1: Gram S = Xb Xb^T (round-1 verbatim) -------------
  const f32x4 fz = {0.f, 0.f, 0.f, 0.f};
  f32x4 acc[2][13];
  #pragma unroll
  for (int i = 0; i < 2; ++i)
    #pragma unroll
    for (int j = 0; j < 13; ++j) acc[i][j] = fz;

  // zero pad rows 200..207 of both slab buffers
  if (tid < 288) { xa0[7200 + tid] = 0u; xa1[7200 + tid] = 0u; }

  float4 vst[7];
  #pragma unroll
  for (int i = 0; i < 7; ++i) {       // stage slab 0 (k=0..63)
    int idx = tid + i * 512;
    if (idx < 3200) {
      int row = idx >> 4, c4 = idx & 15;
      vst[i] = *(const float4*)(xb + row * LL + c4 * 4);
    }
  }
  #pragma unroll
  for (int i = 0; i < 7; ++i) {
    int idx = tid + i * 512;
    if (idx < 3200) {
      int row = idx >> 4, c4 = idx & 15;
      uint2 wv;
      wv.x = bfb(vst[i].x) | (bfb(vst[i].y) << 16);
      wv.y = bfb(vst[i].z) | (bfb(vst[i].w) << 16);
      *(uint2*)&xa0[row * XASTR + c4 * 2] = wv;
    }
  }

  for (int s = 0; s < 16; ++s) {
    __syncthreads();                   // slab s visible
    if (s + 1 < 16) {                  // issue next-slab loads early
      #pragma unroll
      for (int i = 0; i < 7; ++i) {
        int idx = tid + i * 512;
        if (idx < 3200) {
          int row = idx >> 4, c4 = idx & 15;
          vst[i] = *(const float4*)(xb + row * LL + (s + 1) * 64 + c4 * 4);
        }
      }
    }
    const uint32* cur = (s & 1) ? xa1 : xa0;
    #pragma unroll
    for (int ks = 0; ks < 2; ++ks) {
      bf16x8 a0 = *(const bf16x8*)&cur[(rb0 * 16 + lm) * XASTR + ks * 16 + lg * 4];
      bf16x8 a1 = a0;
      if (two) a1 = *(const bf16x8*)&cur[(rb1 * 16 + lm) * XASTR + ks * 16 + lg * 4];
      #pragma unroll
      for (int ct = 0; ct < 13; ++ct) {
        bf16x8 bf = *(const bf16x8*)&cur[(ct * 16 + lm) * XASTR + ks * 16 + lg * 4];
        acc[0][ct] = __builtin_amdgcn_mfma_f32_16x16x32_bf16(a0, bf, acc[0][ct], 0, 0, 0);
        if (two)
          acc[1][ct] = __builtin_amdgcn_mfma_f32_16x16x32_bf16(a1, bf, acc[1][ct], 0, 0, 0);
      }
    }
    if (s + 1 < 16) {                  // write staged regs -> other buffer
      uint32* nxt = (s & 1) ? xa0 : xa1;
      #pragma unroll
      for (int i = 0; i < 7; ++i) {
        int idx = tid + i * 512;
        if (idx < 3200) {
          int row = idx >> 4, c4 = idx & 15;
          uint2 wv;
          wv.x = bfb(vst[i].x) | (bfb(vst[i].y) << 16);
          wv.y = bfb(vst[i].z) | (bfb(vst[i].w) << 16);
          *(uint2*)&nxt[row * XASTR + c4 * 2] = wv;
        }
      }
    }
  }

  // ---------------- norms from Gram diagonal ---------------------------------
  #pragma unroll
  for (int rbi = 0; rbi < 2; ++rbi) {
    if (rbi == 0 || two) {
      int rb = rbi ? rb1 : rb0;
      #pragma unroll
      for (int ct = 0; ct < 13; ++ct) {
        if (ct == rb) {
          #pragma unroll
          for (int r = 0; r < 4; ++r) {
            int ri = lg * 4 + r;
            if (lm == ri) norms[rb * 16 + ri] = sqrtf(acc[rbi][ct][r]);
          }
        }
      }
    }
  }
  __syncthreads();

  // ---------------- softmax rows + (P+I) -> LDS bf16 -------------------------
  float cn[13];
  #pragma unroll
  for (int ct = 0; ct < 13; ++ct) cn[ct] = norms[ct * 16 + lm];

  #pragma unroll
  for (int rbi = 0; rbi < 2; ++rbi) {
    if (rbi == 0 || two) {
      int rb = rbi ? rb1 : rb0;
      #pragma unroll
      for (int r = 0; r < 4; ++r) {
        int grow = rb * 16 + lg * 4 + r;
        float rn = norms[grow];
        float sv[13];
        float m = -INFINITY;
        #pragma unroll
        for (int ct = 0; ct < 13; ++ct) {
          int gc = ct * 16 + lm;
          float sval = acc[rbi][ct][r] / fmaxf(rn * cn[ct], EPSV);
          sval = (gc < CC) ? sval : -INFINITY;
          sv[ct] = sval;
          m = fmaxf(m, sval);
        }
        #pragma unroll
        for (int off = 1; off < 16; off <<= 1) m = fmaxf(m, __shfl_xor(m, off));
        float sum = 0.f;
        #pragma unroll
        for (int ct = 0; ct < 13; ++ct) {
          float e = __expf(sv[ct] - m);
          sv[ct] = e;
          sum += e;
        }
        #pragma unroll
        for (int off = 1; off < 16; off <<= 1) sum += __shfl_xor(sum, off);
        float inv = 1.0f / sum;
        #pragma unroll
        for (int ct = 0; ct < 13; ++ct) {
          int gc = ct * 16 + lm;
          float p = sv[ct] * inv + ((gc == grow) ? 1.0f : 0.0f);   // P += I
          uint32 pb = bfb(p);
          uint32 qb = (uint32)__shfl_xor((int)pb, 1);
          if (!(lane & 1)) pl[grow * PLSTR + ct * 8 + (lm >> 1)] = pb | (qb << 16);
        }
      }
      // zero P cols 200..223 (dw 100..111) for this row-block
      for (int i = lane; i < 256; i += 64) {
        int rr = i >> 4, c = i & 15;
        if (c < 12) pl[(rb * 16 + rr) * PLSTR + 100 + c] = 0u;
      }
    }
  }

  // A-fragments (own rows only; this wave wrote them -> intra-wave, no barrier)
  bf16x8 pa[2][7];
  #pragma unroll
  for (int ks = 0; ks < 7; ++ks) {
    pa[0][ks] = *(const bf16x8*)&pl[(rb0 * 16 + lm) * PLSTR + ks * 16 + lg * 4];
    if (two)
      pa[1][ks] = *(const bf16x8*)&pl[(rb1 * 16 + lm) * PLSTR + ks * 16 + lg * 4];
  }

  // ---------------- Phase 2: out = (P+I) @ Xb, 16 chunks of 64 cols ----------
  // T14: chunk loads issued one iteration ahead, held in regs, written after
  // the barrier. Per thread per chunk: 14 kpairs (kp = p*8+w), col = n0+lane.
  float pva[14], pvb[14];
  #pragma unroll
  for (int p = 0; p < 14; ++p) {       // preload chunk 0
    int kp = p * 8 + w;
    int r0 = kp * 2, r1 = r0 + 1;
    pva[p] = (r0 < CC) ? xb[r0 * LL + lane] : 0.f;
    pvb[p] = (r1 < CC) ? xb[r1 * LL + lane] : 0.f;
  }

  for (int nc = 0; nc < 16; ++nc) {
    const int n0 = nc * 64;
    __syncthreads();                   // xbuf free (nc=0: phase-1 xa dead)
    #pragma unroll
    for (int p = 0; p < 14; ++p) {     // write staged regs -> xbuf
      int kp = p * 8 + w;
      xbuf[lane * XBSTR + kp] = bfb(pva[p]) | (bfb(pvb[p]) << 16);
    }
    __syncthreads();                   // xbuf ready
    if (nc + 1 < 16) {                 // issue next chunk's loads (hide under MFMA)
      const int n1 = (nc + 1) * 64;
      #pragma unroll
      for (int p = 0; p < 14; ++p) {
        int kp = p * 8 + w;
        int r0 = kp * 2, r1 = r0 + 1;
        pva[p] = (r0 < CC) ? xb[r0 * LL + n1 + lane] : 0.f;
        pvb[p] = (r1 < CC) ? xb[r1 * LL + n1 + lane] : 0.f;
      }
    }

    f32x4 acc2[2][4];
    #pragma unroll
    for (int i = 0; i < 2; ++i)
      #pragma unroll
      for (int j = 0; j < 4; ++j) acc2[i][j] = fz;

    #pragma unroll
    for (int ks = 0; ks < 7; ++ks) {   // K = 224 (P cols 200..223 zero)
      #pragma unroll
      for (int ct = 0; ct < 4; ++ct) {
        bf16x8 b = *(const bf16x8*)&xbuf[(ct * 16 + lm) * XBSTR + ks * 16 + lg * 4];
        acc2[0][ct] = __builtin_amdgcn_mfma_f32_16x16x32_bf16(pa[0][ks], b, acc2[0][ct], 0, 0, 0);
        if (two)
          acc2[1][ct] = __builtin_amdgcn_mfma_f32_16x16x32_bf16(pa[1][ks], b, acc2[1][ct], 0, 0, 0);
      }
    }

    #pragma unroll
    for (int rbi = 0; rbi < 2; ++rbi) {
      if (rbi == 0 || two) {
        int rb = rbi ? rb1 : rb0;
        #pragma unroll
        for (int ct = 0; ct < 4; ++ct) {
          #pragma unroll
          for (int r = 0; r < 4; ++r) {
            int grow = rb * 16 + lg * 4 + r;
            if (grow < CC) ob[grow * LL + n0 + ct * 16 + lm] = acc2[rbi][ct][r];
          }
        }
      }
    }
  }
}

extern "C" void kernel_launch(void* const* d_in, const int* in_sizes, int n_in,
                              void* d_out, int out_size, void* d_ws, size_t ws_size,
                              hipStream_t stream) {
  const float* x = (const float*)d_in[0];
  float* out = (float*)d_out;
  const int B = in_sizes[0] / (CC * LL);   // 256
  spe_attn_kernel<<<dim3(B), dim3(512), 0, stream>>>(x, out);
}